// Round 1
// baseline (264.382 us; speedup 1.0000x reference)
//
#include <hip/hip_runtime.h>
#include <math.h>

// LIF recurrence: v_t = v_{t-1} * decay * (1 - z_{t-1}) + x_t ; z_t = (v_t > 0.3)
// Shapes: x_seq [B=128, T=2048, H=128] f32; v0,z0 [B,H]; decay_raw [H]; out [B,T,H] f32.
//
// Parallelism: one thread per (b,h) serial chain -> 16384 threads.
// 64-thread blocks (1 wave) so 256 blocks spread over all 256 CUs (max HBM spread).
// Time loop software-pipelined in 32-step chunks (registers) to hide HBM latency.

constexpr int Bdim = 128;
constexpr int Tdim = 2048;
constexpr int Hdim = 128;
constexpr int U = 32;           // time-chunk / prefetch depth
constexpr float VTH = 0.3f;

__global__ __launch_bounds__(64) void lif_kernel(
    const float* __restrict__ x,
    const float* __restrict__ v0,
    const float* __restrict__ z0,
    const float* __restrict__ decay_raw,
    float* __restrict__ out)
{
    const int tid = blockIdx.x * 64 + threadIdx.x;   // 0 .. 16383
    const int b = tid >> 7;          // / Hdim
    const int h = tid & (Hdim - 1);

    const float decay = 1.0f / (1.0f + expf(-decay_raw[h]));
    float v = v0[tid];
    float z = z0[tid];

    const float* xp = x   + (size_t)b * Tdim * Hdim + h;
    float*       op = out + (size_t)b * Tdim * Hdim + h;

    float cur[U], nxt[U];

#pragma unroll
    for (int u = 0; u < U; ++u) cur[u] = xp[u * Hdim];

    for (int tc = 0; tc < Tdim; tc += U) {
        // Prefetch next chunk (independent loads, in flight during compute below)
        if (tc + U < Tdim) {
            const float* xn = xp + (size_t)(tc + U) * Hdim;
#pragma unroll
            for (int u = 0; u < U; ++u) nxt[u] = xn[u * Hdim];
        }
        // Serial recurrence on current chunk
#pragma unroll
        for (int u = 0; u < U; ++u) {
            const float vd = v * decay;
            v = ((z > 0.5f) ? 0.0f : vd) + cur[u];     // exact: (1-z) mult with z in {0,1}
            z = (v > VTH) ? 1.0f : 0.0f;
            op[(size_t)(tc + u) * Hdim] = z;
        }
#pragma unroll
        for (int u = 0; u < U; ++u) cur[u] = nxt[u];
    }
}

extern "C" void kernel_launch(void* const* d_in, const int* in_sizes, int n_in,
                              void* d_out, int out_size, void* d_ws, size_t ws_size,
                              hipStream_t stream) {
    const float* x         = (const float*)d_in[0];
    const float* v0        = (const float*)d_in[1];
    const float* z0        = (const float*)d_in[2];
    const float* decay_raw = (const float*)d_in[3];
    float* out = (float*)d_out;

    const int total = Bdim * Hdim;        // 16384 threads
    lif_kernel<<<total / 64, 64, 0, stream>>>(x, v0, z0, decay_raw, out);
}

// Round 2
// 248.000 us; speedup vs baseline: 1.0661x; 1.0661x over previous
//
#include <hip/hip_runtime.h>
#include <math.h>

// LIF recurrence: v_t = v_{t-1}*decay*(1-z_{t-1}) + x_t ; z_t = (v_t > 0.3)
// x [B=128,T=2048,H=128] f32; out [B,T,H] f32 spikes.
//
// R2 design: one wave (64 threads) per (b, h-half) -> 256 blocks.
// x streamed via __builtin_amdgcn_global_load_lds (zero-VGPR outstanding loads:
// 32 insts x 1KB in flight per wave = 8 MB device-wide >> 1.6 MB Little's-law need).
// LDS double buffer: 2 x [128 timesteps x 64 h] = 64 KB. __syncthreads per chunk
// drains the tile's loads (m97 pattern); drain tail hidden under 6.4K-cyc BW budget.

constexpr int Bdim = 128;
constexpr int Tdim = 2048;
constexpr int Hdim = 128;
constexpr int HW   = 64;    // h-columns per wave
constexpr int U    = 128;   // timesteps per tile (tile = 32 KB)
constexpr float VTH = 0.3f;

typedef const __attribute__((address_space(1))) void* gptr_t;
typedef __attribute__((address_space(3))) void* lptr_t;

__global__ __launch_bounds__(64) void lif_kernel(
    const float* __restrict__ x,
    const float* __restrict__ v0,
    const float* __restrict__ z0,
    const float* __restrict__ decay_raw,
    float* __restrict__ out)
{
    __shared__ float lds[2][U][HW];

    const int lane = threadIdx.x;
    const int w  = blockIdx.x;       // 0..255
    const int b  = w >> 1;
    const int h0 = (w & 1) * HW;
    const int h  = h0 + lane;

    const float decay = 1.0f / (1.0f + expf(-decay_raw[h]));
    float v = v0[b * Hdim + h];
    float z = z0[b * Hdim + h];

    const float* xbase = x   + (size_t)b * Tdim * Hdim + h0;
    float*       obase = out + (size_t)b * Tdim * Hdim + h0 + lane;

    // global_load_lds width=16: lane i writes LDS base + i*16.
    // Inst j covers rows 4j..4j+3 of the tile: lane i reads
    // x[t0 + 4j + i/16][h0 + (i%16)*4 ..+3]  -> LDS [t][h] row-major. 16B-aligned.
    const int sub_r = lane >> 4;          // 0..3
    const int sub_c = (lane & 15) * 4;    // float col within 64

    auto issue_tile = [&](int t0, int buf) {
        const float* g = xbase + (size_t)t0 * Hdim + sub_c + (size_t)sub_r * Hdim;
        #pragma unroll
        for (int j = 0; j < U / 4; ++j) {
            __builtin_amdgcn_global_load_lds(
                (gptr_t)(const void*)(g + (size_t)(4 * j) * Hdim),
                (lptr_t)(void*)&lds[buf][4 * j][0],
                16, 0, 0);
        }
    };

    issue_tile(0, 0);
    __syncthreads();                       // tile 0 resident

    int buf = 0;
    for (int tc = 0; tc < Tdim; tc += U) {
        if (tc + U < Tdim) issue_tile(tc + U, buf ^ 1);   // in flight during compute

        float* op = obase + (size_t)tc * Hdim;
        #pragma unroll 16
        for (int tl = 0; tl < U; ++tl) {
            const float xv = lds[buf][tl][lane];
            const float vd = v * decay;
            v = ((z > 0.5f) ? 0.0f : vd) + xv;   // exact: z in {0,1}
            z = (v > VTH) ? 1.0f : 0.0f;
            op[(size_t)tl * Hdim] = z;
        }

        __syncthreads();                   // next tile's loads (and stores) drained
        buf ^= 1;
    }
}

extern "C" void kernel_launch(void* const* d_in, const int* in_sizes, int n_in,
                              void* d_out, int out_size, void* d_ws, size_t ws_size,
                              hipStream_t stream) {
    const float* x         = (const float*)d_in[0];
    const float* v0        = (const float*)d_in[1];
    const float* z0        = (const float*)d_in[2];
    const float* decay_raw = (const float*)d_in[3];
    float* out = (float*)d_out;

    lif_kernel<<<Bdim * Hdim / HW, 64, 0, stream>>>(x, v0, z0, decay_raw, out);
}

// Round 3
// 240.768 us; speedup vs baseline: 1.0981x; 1.0300x over previous
//
#include <hip/hip_runtime.h>
#include <math.h>

// LIF recurrence: v_t = v_{t-1}*decay*(1-z_{t-1}) + x_t ; z_t = (v_t > 0.3)
// x [B=128,T=2048,H=128] f32; out [B,T,H] f32 spikes.
//
// R3: 256 blocks x 512 threads (8 waves). Wave 0 computes the block's 64 serial
// chains; ALL 8 waves split the tile's 32 global_load_lds insts (8 independent
// per-wave DMA queues -> 8x outstanding vs R2's single wave). 4-buffer LDS ring
// (128 KB), lookahead-2: each tile gets ~2 iterations of flight time.
// z is written back into the consumed x tile (ds_write, lgkm domain) and flushed
// next iteration by all waves as coalesced dwordx4 stores.

constexpr int Bdim = 128;
constexpr int Tdim = 2048;
constexpr int Hdim = 128;
constexpr int HW   = 64;     // chains per block
constexpr int U    = 128;    // timesteps per tile (32 KB)
constexpr int NBUF = 4;      // LDS ring depth (128 KB)
constexpr int NW   = 8;      // waves per block
constexpr int NTILE = Tdim / U;   // 16
constexpr float VTH = 0.3f;

typedef const __attribute__((address_space(1))) void* gptr_t;
typedef __attribute__((address_space(3))) void* lptr_t;

__global__ __launch_bounds__(NW * 64) void lif_kernel(
    const float* __restrict__ x,
    const float* __restrict__ v0,
    const float* __restrict__ z0,
    const float* __restrict__ decay_raw,
    float* __restrict__ out)
{
    __shared__ float lds[NBUF][U][HW];

    const int tid  = threadIdx.x;
    const int wave = tid >> 6;
    const int lane = tid & 63;
    const int blk  = blockIdx.x;          // 0..255
    const int b    = blk >> 1;
    const int h0   = (blk & 1) * HW;

    const float* xbase = x   + (size_t)b * Tdim * Hdim + h0;
    float*       obase = out + (size_t)b * Tdim * Hdim + h0;

    // DMA inst jj covers tile rows [4jj,4jj+4): lane i -> row 4jj+(i>>4), col (i&15)*4.
    // HW writes lane i at lds_base + i*16 B == lds[buf][4jj + i/16][(i%16)*4]. Matches.
    const int sub = (lane >> 4) * Hdim + (lane & 15) * 4;   // per-lane global float offset

    auto fill = [&](int tile, int buf) {
        const float* g = xbase + (size_t)tile * U * Hdim + sub;
        #pragma unroll
        for (int q = 0; q < 4; ++q) {
            const int jj = wave * 4 + q;               // 8 waves x 4 = 32 insts
            __builtin_amdgcn_global_load_lds(
                (gptr_t)(const void*)(g + (size_t)(4 * jj) * Hdim),
                (lptr_t)(void*)&lds[buf][4 * jj][0],
                16, 0, 0);
        }
    };

    auto flush = [&](int tile, int buf) {              // z tile -> global, dwordx4
        #pragma unroll
        for (int q = 0; q < 4; ++q) {
            const int s   = wave * 4 + q;              // 32 store insts, 1 KB each
            const int row = 4 * s + (lane >> 4);
            const int col = (lane & 15) * 4;
            const float4 vv = *(const float4*)&lds[buf][row][col];
            *(float4*)(obase + (size_t)(tile * U + row) * Hdim + col) = vv;
        }
    };

    float decay = 0.f, v = 0.f, z = 0.f;
    if (wave == 0) {
        decay = 1.0f / (1.0f + expf(-decay_raw[h0 + lane]));
        v = v0[b * Hdim + h0 + lane];
        z = z0[b * Hdim + h0 + lane];
    }

    fill(0, 0);
    fill(1, 1);
    __syncthreads();                                   // tiles 0,1 resident

    for (int k = 0; k < NTILE; ++k) {
        if (k + 2 < NTILE) fill(k + 2, (k + 2) % NBUF);
        if (k >= 1)        flush(k - 1, (k - 1) % NBUF);

        if (wave == 0) {
            const int cb = k % NBUF;
            #pragma unroll 16
            for (int tl = 0; tl < U; ++tl) {
                const float xv = lds[cb][tl][lane];
                const float vd = v * decay;
                v = ((z > 0.5f) ? 0.0f : vd) + xv;     // exact: z in {0,1}
                z = (v > VTH) ? 1.0f : 0.0f;
                lds[cb][tl][lane] = z;                 // overwrite consumed x with z
            }
        }
        __syncthreads();
    }
    flush(NTILE - 1, (NTILE - 1) % NBUF);              // final z tile
}

extern "C" void kernel_launch(void* const* d_in, const int* in_sizes, int n_in,
                              void* d_out, int out_size, void* d_ws, size_t ws_size,
                              hipStream_t stream) {
    const float* x         = (const float*)d_in[0];
    const float* v0        = (const float*)d_in[1];
    const float* z0        = (const float*)d_in[2];
    const float* decay_raw = (const float*)d_in[3];
    float* out = (float*)d_out;

    lif_kernel<<<Bdim * Hdim / HW, NW * 64, 0, stream>>>(x, v0, z0, decay_raw, out);
}